// Round 1
// 913.393 us; speedup vs baseline: 1.2669x; 1.2669x over previous
//
#include <hip/hip_runtime.h>

// ---------- helpers ----------

__device__ __forceinline__ unsigned short f2bf(float f) {
    // round-to-nearest-even fp32 -> bf16 (no NaN inputs here)
    unsigned u = __float_as_uint(f);
    unsigned r = (u + 0x7fffu + ((u >> 16) & 1u)) >> 16;
    return (unsigned short)r;
}

__device__ __forceinline__ float quant1(float v) {
    // bit_ste: clamp [-1,1], round(|v|*255)/255 (round-half-even), restore sign
    float a = fminf(fabsf(v), 1.0f);
    return copysignf(rintf(a * 255.0f) * (1.0f / 255.0f), v);
}

__device__ __forceinline__ void load_lds16(const void* g, void* l) {
    // global -> LDS direct DMA, 16B per lane; LDS dest = wave-uniform base + lane*16
    __builtin_amdgcn_global_load_lds(
        (const __attribute__((address_space(1))) void*)g,
        (__attribute__((address_space(3))) void*)l,
        16, 0, 0);
}

typedef __attribute__((ext_vector_type(8))) unsigned short u16x8;
typedef __attribute__((ext_vector_type(8))) short bf16x8;
typedef __attribute__((ext_vector_type(4))) float f32x4;

// ---------- conversion kernels (8 elem/thread, 16B stores) ----------

__global__ void cvt_x_kernel(const float4* __restrict__ x, u16x8* __restrict__ o, int n8) {
    int i = blockIdx.x * blockDim.x + threadIdx.x;
    if (i >= n8) return;
    float4 a = x[2 * i], b = x[2 * i + 1];
    u16x8 r;
    r[0] = f2bf(a.x); r[1] = f2bf(a.y); r[2] = f2bf(a.z); r[3] = f2bf(a.w);
    r[4] = f2bf(b.x); r[5] = f2bf(b.y); r[6] = f2bf(b.z); r[7] = f2bf(b.w);
    o[i] = r;
}

__global__ void quant_w_kernel(const float4* __restrict__ w, u16x8* __restrict__ o, int n8) {
    int i = blockIdx.x * blockDim.x + threadIdx.x;
    if (i >= n8) return;
    float4 a = w[2 * i], b = w[2 * i + 1];
    u16x8 r;
    r[0] = f2bf(quant1(a.x)); r[1] = f2bf(quant1(a.y));
    r[2] = f2bf(quant1(a.z)); r[3] = f2bf(quant1(a.w));
    r[4] = f2bf(quant1(b.x)); r[5] = f2bf(quant1(b.y));
    r[6] = f2bf(quant1(b.z)); r[7] = f2bf(quant1(b.w));
    o[i] = r;
}

// ---------- 256x256 8-phase bf16 MFMA GEMM: C = A[M,K] * W[N,K]^T + q(bias) ----------
//
// Structure (T1+T2+T3+T4+T5):
//   BM=BN=256, BK=64, 512 threads = 8 waves as 2(M)x4(N); wave owns 128x64 out.
//   LDS 128 KiB: 2 buffers x (A[256][64] + B[256][64]) bf16.
//   Iteration = 2 K-tiles = 8 phases. Phase q of a K-tile computes m-frags {2q,2q+1}
//   x all 4 n-frags x K=64 (16 MFMA); B fragments (8 x ds_read_b128) loaded at q==0
//   and held in regs for the K-tile.
//   Stage schedule (1 half-tile = 128 rows = 2 global_load_lds/thread per phase):
//     p0: A(t+1)-lo  p1: A(t+1)-hi   (buf1 A; free after prev p7)
//     p2: B(t+2)-lo  p3: B(t+2)-hi   (buf0 B; free after p0)
//     p4: A(t+2)-lo  p5: A(t+2)-hi   (buf0 A; free after p3)
//     p6: B(t+3)-lo  p7: B(t+3)-hi   (buf1 B; free after p4)
//   Counted waits: vmcnt(4) at p3 (drains B(t+1)@prev p6/p7 + A(t+1)@p0/p1 — exactly
//   what p4-7 read) and at p7 (drains B(t+2)@p2/p3 + A(t+2)@p4/p5 — what next p0-3
//   read). Per-wave outstanding: 4 -> 12 -> 4 each half-iteration; never drains to 0.
//   Last iteration stages wrapped K-tiles (in-bounds, never consumed).
//
// Bank-conflict swizzle (fetch-side, since global_load_lds dest is linear):
//   physical k-chunk pc holds logical pc ^ (row&7); fragment reads use
//   pc = lc ^ (row&7) -> each 16-lane fragment read covers all 32 banks exactly
//   twice per 16 lanes (uniform, conflict-free).

#define BM 256
#define BN 256
#define BK 64

// LDS region element base: region (buf*2 + mat), each 256*64 = 16384 elements
template<int SBUF, int SMAT, int SHALF>
__device__ __forceinline__ void stage_half(
    const unsigned short* __restrict__ gA,   // per-lane swizzled base (row tileM+srow, col scol)
    const unsigned short* __restrict__ gB,
    unsigned short* lds, int skt, int K, int wave)
{
    const unsigned short* g = (SMAT == 0) ? gA : gB;
    const int r0 = SHALF * 128 + wave * 16;
    const int sbase = (SBUF * 2 + SMAT) * 16384 + r0 * 64;
    const unsigned short* g0 = g + (size_t)r0 * K + (size_t)skt * 64;
    load_lds16(g0, &lds[sbase]);
    load_lds16(g0 + (size_t)8 * K, &lds[sbase + 512]);
}

template<int Q, int CBUF, int SBUF, int SMAT, int SHALF, int WAITN>
__device__ __forceinline__ void phase(
    f32x4 (&acc)[8][4], bf16x8 (&bv)[4][2],
    const unsigned short* __restrict__ gA,
    const unsigned short* __restrict__ gB,
    unsigned short* lds, int skt, int K,
    int wave, int lane, int wmBase, int wnBase)
{
    constexpr int TQ = Q & 3;
    const int l15 = lane & 15, lq = lane >> 4;

    // ---- ds_read fragments (swizzled) ----
    bf16x8 av[2][2];
    {
        const int abase = (CBUF * 2 + 0) * 16384;
#pragma unroll
        for (int mfl = 0; mfl < 2; ++mfl) {
            const int row = wmBase + (TQ * 2 + mfl) * 16 + l15;
#pragma unroll
            for (int ks = 0; ks < 2; ++ks) {
                const int pc = (ks * 4 + lq) ^ (row & 7);
                av[mfl][ks] = *(const bf16x8*)&lds[abase + row * 64 + pc * 8];
            }
        }
    }
    if (TQ == 0) {
        const int bbase = (CBUF * 2 + 1) * 16384;
#pragma unroll
        for (int nf = 0; nf < 4; ++nf) {
            const int row = wnBase + nf * 16 + l15;
#pragma unroll
            for (int ks = 0; ks < 2; ++ks) {
                const int pc = (ks * 4 + lq) ^ (row & 7);
                bv[nf][ks] = *(const bf16x8*)&lds[bbase + row * 64 + pc * 8];
            }
        }
    }

    // ---- stage one half-tile of a future K-tile ----
    stage_half<SBUF, SMAT, SHALF>(gA, gB, lds, skt, K, wave);

    // ---- counted vmcnt (never 0 in main loop) ----
    if constexpr (WAITN >= 0)
        asm volatile("s_waitcnt vmcnt(%0)" :: "i"(WAITN) : "memory");

    __builtin_amdgcn_s_barrier();
    asm volatile("s_waitcnt lgkmcnt(0)" ::: "memory");
    __builtin_amdgcn_sched_barrier(0);

    __builtin_amdgcn_s_setprio(1);
#pragma unroll
    for (int mfl = 0; mfl < 2; ++mfl)
#pragma unroll
        for (int nf = 0; nf < 4; ++nf) {
            acc[TQ * 2 + mfl][nf] = __builtin_amdgcn_mfma_f32_16x16x32_bf16(
                av[mfl][0], bv[nf][0], acc[TQ * 2 + mfl][nf], 0, 0, 0);
            acc[TQ * 2 + mfl][nf] = __builtin_amdgcn_mfma_f32_16x16x32_bf16(
                av[mfl][1], bv[nf][1], acc[TQ * 2 + mfl][nf], 0, 0, 0);
        }
    __builtin_amdgcn_s_setprio(0);
    __builtin_amdgcn_s_barrier();
}

__global__ __launch_bounds__(512, 2) void gemm256(
    const unsigned short* __restrict__ A,   // [M][K] bf16 bits
    const unsigned short* __restrict__ Bw,  // [N][K] bf16 bits
    const float* __restrict__ bias,         // [N] fp32 (quantized in epilogue)
    float* __restrict__ C,                  // [M][N] fp32
    int M, int N, int K)
{
    __shared__ unsigned short lds[4 * 256 * 64];   // 128 KiB: {A0,B0,A1,B1}

    const int tid  = threadIdx.x;
    const int wave = tid >> 6;
    const int lane = tid & 63;
    const int wmBase = (wave >> 2) * 128;   // wave row: 0 or 128
    const int wnBase = (wave & 3) * 64;     // wave col: 0,64,128,192

    // XCD-aware bijective block swizzle (nwg % 8 == 0 here: 1024 blocks)
    const int bid = blockIdx.x;
    const int nwg = gridDim.x;
    int swz = bid;
    if ((nwg & 7) == 0) swz = (bid & 7) * (nwg >> 3) + (bid >> 3);
    const int ntn = N / BN;
    const int tileM = (swz / ntn) * BM;
    const int tileN = (swz % ntn) * BN;

    // per-lane staging base: row = tile + (lane>>3), col chunk = (lane&7)^(lane>>3)
    const int srow = lane >> 3;
    const int scol = ((lane & 7) ^ srow) * 8;
    const unsigned short* gA = A  + (size_t)(tileM + srow) * K + scol;
    const unsigned short* gB = Bw + (size_t)(tileN + srow) * K + scol;

    // ---- prologue: tile0 A+B -> buf0, tile1 B -> buf1 (A(1) staged at p0/p1) ----
    stage_half<0, 0, 0>(gA, gB, lds, 0, K, wave);
    stage_half<0, 0, 1>(gA, gB, lds, 0, K, wave);
    stage_half<0, 1, 0>(gA, gB, lds, 0, K, wave);
    stage_half<0, 1, 1>(gA, gB, lds, 0, K, wave);
    stage_half<1, 1, 0>(gA, gB, lds, 1, K, wave);
    stage_half<1, 1, 1>(gA, gB, lds, 1, K, wave);

    f32x4 acc[8][4];
#pragma unroll
    for (int i = 0; i < 8; ++i)
#pragma unroll
        for (int j = 0; j < 4; ++j) acc[i][j] = (f32x4){0.f, 0.f, 0.f, 0.f};
    bf16x8 bv[4][2];

    asm volatile("s_waitcnt vmcnt(4)" ::: "memory");  // tile0 resident; B(1) in flight
    __builtin_amdgcn_s_barrier();

    const int nkt = K >> 6;                 // K-tiles of 64
    for (int it = 0; it < (nkt >> 1); ++it) {
        const int t  = it << 1;
        const int k1 = t + 1;
        int k2 = t + 2; if (k2 >= nkt) k2 -= nkt;   // wrapped: staged, never read
        int k3 = t + 3; if (k3 >= nkt) k3 -= nkt;
        //        Q  CB  SB SM SH  WAIT
        phase<0, 0,  1, 0, 0, -1>(acc, bv, gA, gB, lds, k1, K, wave, lane, wmBase, wnBase);
        phase<1, 0,  1, 0, 1, -1>(acc, bv, gA, gB, lds, k1, K, wave, lane, wmBase, wnBase);
        phase<2, 0,  0, 1, 0, -1>(acc, bv, gA, gB, lds, k2, K, wave, lane, wmBase, wnBase);
        phase<3, 0,  0, 1, 1,  4>(acc, bv, gA, gB, lds, k2, K, wave, lane, wmBase, wnBase);
        phase<4, 1,  0, 0, 0, -1>(acc, bv, gA, gB, lds, k2, K, wave, lane, wmBase, wnBase);
        phase<5, 1,  0, 0, 1, -1>(acc, bv, gA, gB, lds, k2, K, wave, lane, wmBase, wnBase);
        phase<6, 1,  1, 1, 0, -1>(acc, bv, gA, gB, lds, k3, K, wave, lane, wmBase, wnBase);
        phase<7, 1,  1, 1, 1,  4>(acc, bv, gA, gB, lds, k3, K, wave, lane, wmBase, wnBase);
    }

    // drain DMA before endpgm (LDS may be reallocated to a new block)
    asm volatile("s_waitcnt vmcnt(0)" ::: "memory");

    // ---- epilogue: C/D layout col=lane&15, row=(lane>>4)*4+reg ----
    const int col0  = lane & 15;
    const int rquad = (lane >> 4) * 4;
#pragma unroll
    for (int nf = 0; nf < 4; ++nf) {
        const int gn = tileN + wnBase + nf * 16 + col0;
        const float qb = quant1(bias[gn]);
#pragma unroll
        for (int mf = 0; mf < 8; ++mf) {
            const int gm = tileM + wmBase + mf * 16 + rquad;
#pragma unroll
            for (int r = 0; r < 4; ++r)
                C[(size_t)(gm + r) * N + gn] = acc[mf][nf][r] + qb;
        }
    }
}

// ---------- slow-but-correct fallback (only if ws too small / odd shape) ----------

__global__ void gemm_fallback(const float* __restrict__ x, const float* __restrict__ w,
                              const float* __restrict__ bias, float* __restrict__ out,
                              int M, int N, int K)
{
    int idx = blockIdx.x * 256 + threadIdx.x;
    if (idx >= M * N) return;
    int m = idx / N, n = idx - m * N;
    const float* xr = x + (size_t)m * K;
    const float* wr = w + (size_t)n * K;
    float s = 0.f;
    for (int k = 0; k < K; k++) s += xr[k] * quant1(wr[k]);
    out[idx] = s + quant1(bias[n]);
}

// ---------- launch ----------

extern "C" void kernel_launch(void* const* d_in, const int* in_sizes, int n_in,
                              void* d_out, int out_size, void* d_ws, size_t ws_size,
                              hipStream_t stream) {
    const float* x    = (const float*)d_in[0];
    const float* w    = (const float*)d_in[1];
    const float* bias = (const float*)d_in[2];
    float* out = (float*)d_out;

    const int N = in_sizes[2];           // 4096
    const int K = in_sizes[1] / N;       // 4096
    const int M = in_sizes[0] / K;       // 16384

    size_t qw_bytes = (size_t)N * K * 2;
    size_t xb_bytes = (size_t)M * K * 2;

    if (ws_size >= qw_bytes + xb_bytes &&
        (M % BM) == 0 && (N % BN) == 0 && (K % (2 * BK)) == 0) {
        unsigned short* qw = (unsigned short*)d_ws;
        unsigned short* xb = (unsigned short*)((char*)d_ws + qw_bytes);

        int nw8 = (N * K) / 8;
        quant_w_kernel<<<(nw8 + 255) / 256, 256, 0, stream>>>(
            (const float4*)w, (u16x8*)qw, nw8);

        int nx8 = (M * K) / 8;
        cvt_x_kernel<<<(nx8 + 255) / 256, 256, 0, stream>>>(
            (const float4*)x, (u16x8*)xb, nx8);

        int nwg = (M / BM) * (N / BN);
        gemm256<<<nwg, 512, 0, stream>>>(xb, qw, bias, out, M, N, K);
    } else {
        int total = M * N;
        gemm_fallback<<<(total + 255) / 256, 256, 0, stream>>>(x, w, bias, out, M, N, K);
    }
}